// Round 5
// baseline (4482.649 us; speedup 1.0000x reference)
//
#include <hip/hip_runtime.h>

#define TPB    256
#define NF     32
#define T_TOT  406
#define LLEN   2048
#define NPAIR  496
#define CPW    7            // windows per block; 58*7 = 406 exactly
#define NCH    58           // chunks per batch
#define ROWS   56           // staged rows (4-aligned segment start, 52 needed + pad)
#define TSTR   9            // out-tile row stride (floats) — coprime with 32 banks

__global__ __launch_bounds__(TPB, 6)
void tscorr_kernel(const float* __restrict__ x, float* __restrict__ out) {
    __shared__ float fs[ROWS * 32];      //  7168 B, [row][f], row stride = 128B
    __shared__ float ot[NPAIR * TSTR];   // 17856 B, f32 out tile, stride 9

    const int tid = threadIdx.x;

    // XCD-aware decode: batch b -> XCD b%8 (consecutive same-XCD blocks walk
    // the chunks of one batch => x[b] L2-resident, output lines combine in one L2)
    const int n     = blockIdx.x;
    const int xcd   = n & 7;
    const int slot  = n >> 3;            // 0 .. 32*58-1
    const int bidx  = slot / NCH;        // 0..31
    const int chunk = slot - bidx * NCH; // 0..57
    const int b     = xcd + 8 * bidx;

    const int l0     = chunk * (CPW * 5);    // chunk*35
    const int lstart = l0 & ~3;              // 16B-aligned segment start
    const int off    = l0 - lstart;          // 0..3
    const float* xb  = x + (size_t)b * NF * LLEN;

    // ---------------- Phase A: coalesced float4 loads -> fs[row][f] ----------------
    {
        const int f  = tid >> 3;             // 0..31
        const int p4 = tid & 7;              // 0..7
        #pragma unroll
        for (int it = 0; it < 2; ++it) {
            int grp = p4 + it * 8;           // 0..15, need 0..13
            if (grp < 14) {
                int pos = grp * 4;           // 0..52
                const float4 v = *(const float4*)&xb[f * LLEN + lstart + pos]; // 16B aligned, in-bounds (lstart+55 <= 2047)
                fs[(pos + 0) * 32 + f] = v.x;
                fs[(pos + 1) * 32 + f] = v.y;
                fs[(pos + 2) * 32 + f] = v.z;
                fs[(pos + 3) * 32 + f] = v.w;
            }
        }
    }
    __syncthreads();

    // ---------------- mapping: thread = (pair-block pb, window tl) ----------------
    const bool active = (tid < 252);
    const int  tl = tid / 36;                // 0..6
    const int  pb = tid - tl * 36;           // 0..35
    int bi = 0;
    {
        int rem = active ? pb : 0;
        while (rem >= 8 - bi) { rem -= 8 - bi; ++bi; }
        bi = bi; // bj below
    }
    int rem2 = active ? pb : 0;
    int bi2 = 0;
    while (rem2 >= 8 - bi2) { rem2 -= 8 - bi2; ++bi2; }
    const int bbi = bi2;
    const int bbj = bi2 + rem2;

    if (active) {
        float A[4][4];
        float Si[4], Sj[4], Gi[4], Gj[4];
        #pragma unroll
        for (int r = 0; r < 4; ++r) {
            Si[r] = Sj[r] = Gi[r] = Gj[r] = 0.f;
            #pragma unroll
            for (int c = 0; c < 4; ++c) A[r][c] = 0.f;
        }

        // window rows: fs rows [off + tl*5, +20)
        const float* pi = &fs[(off + tl * 5) * 32 + bbi * 4];
        const float* pj = &fs[(off + tl * 5) * 32 + bbj * 4];
        #pragma unroll
        for (int kk = 0; kk < 20; ++kk) {
            const float4 vi = *(const float4*)&pi[kk * 32];   // base + imm offset
            const float4 vj = *(const float4*)&pj[kk * 32];
            float xi[4] = {vi.x, vi.y, vi.z, vi.w};
            float xj[4] = {vj.x, vj.y, vj.z, vj.w};
            #pragma unroll
            for (int r = 0; r < 4; ++r) {
                #pragma unroll
                for (int c = 0; c < 4; ++c)
                    A[r][c] = fmaf(xi[r], xj[c], A[r][c]);
                Si[r] += xi[r];
                Sj[r] += xj[r];
                Gi[r] = fmaf(xi[r], xi[r], Gi[r]);
                Gj[r] = fmaf(xj[r], xj[r], Gj[r]);
            }
        }

        // self-computed stats (no cross-thread exchange needed)
        float mi[4], ni[4], mj[4], nj[4];
        #pragma unroll
        for (int r = 0; r < 4; ++r) {
            mi[r] = Si[r] * 0.05f;
            ni[r] = sqrtf(fmaxf(Gi[r] - 20.f * mi[r] * mi[r], 0.f));
            mj[r] = Sj[r] * 0.05f;
            nj[r] = sqrtf(fmaxf(Gj[r] - 20.f * mj[r] * mj[r], 0.f));
        }

        #pragma unroll
        for (int r = 0; r < 4; ++r) {
            const int fi = bbi * 4 + r;
            #pragma unroll
            for (int c = 0; c < 4; ++c) {
                const int fj = bbj * 4 + c;
                if (fj > fi) {
                    const int p   = fi * (63 - fi) / 2 + (fj - fi - 1);
                    const float num = A[r][c] - 20.f * mi[r] * mj[c];
                    const float den = ni[r] * nj[c] + 1e-8f;
                    ot[p * TSTR + tl] = num * __builtin_amdgcn_rcpf(den);
                }
            }
        }
    }
    __syncthreads();

    // ---------------- sweep: ot[p][0..6] -> out[b][p][chunk*7 + 0..6] ----------------
    float* ob = out + (size_t)b * NPAIR * T_TOT + chunk * CPW;
    for (int k = tid; k < NPAIR * CPW; k += TPB) {
        const int p  = k / CPW;
        const int tw = k - p * CPW;
        ob[(size_t)p * T_TOT + tw] = ot[p * TSTR + tw];
    }
}

extern "C" void kernel_launch(void* const* d_in, const int* in_sizes, int n_in,
                              void* d_out, int out_size, void* d_ws, size_t ws_size,
                              hipStream_t stream) {
    (void)in_sizes; (void)n_in; (void)out_size; (void)d_ws; (void)ws_size;
    const float* x = (const float*)d_in[0];
    float* out     = (float*)d_out;
    const int nblocks = 8 * 32 * NCH;    // 14848
    hipLaunchKernelGGL(tscorr_kernel, dim3(nblocks), dim3(TPB), 0, stream, x, out);
}

// Round 6
// 808.374 us; speedup vs baseline: 5.5453x; 5.5453x over previous
//
#include <hip/hip_runtime.h>

#define TPB    768
#define NF     32
#define T_TOT  406
#define LLEN   2048
#define NPAIR  496
#define TSLAB  58           // t-windows per slab; 7*58 = 406 exactly
#define NSLAB  7
#define LSEG   308          // staged l rows: off(<=2) + 57*5 + 20 <= 307
#define FSW    36           // fs row stride (words): 144B, 16B-aligned, 8-distinct-start banks
#define STSTR  59           // st row stride (float2)

__global__ __launch_bounds__(TPB)
void tscorr_kernel(const float* __restrict__ x, float* __restrict__ out) {
    __shared__ float  fs[LSEG * FSW];     // 44352 B, transposed [l][f]
    __shared__ float2 st[NF * STSTR];     // 15104 B, (mu, norm) per (f, t)

    const int tid = threadIdx.x;

    // decode: all 21 blocks of batch b land on XCD b%8, consecutively
    const int n    = blockIdx.x;
    const int xcd  = n & 7;
    const int slot = n >> 3;              // 0..671
    const int bidx = slot / 21;           // 0..31
    const int rem  = slot - bidx * 21;    // 0..20
    const int g    = rem / 7;             // pb-group 0..2
    const int s    = rem - g * 7;         // t-slab 0..6
    const int b    = xcd + 8 * bidx;

    const int l0     = s * (TSLAB * 5);   // s*290
    const int lstart = l0 & ~3;           // multiple of 4
    const int off    = l0 - lstart;       // 0 or 2

    const float* xb = x + (size_t)b * NF * LLEN;

    // ---------- stage all 32 feature rows, transposed ----------
    // lanes write consecutive l within a feature: coalesced global reads,
    // ds_write banks step 36 mod 32 = 4 -> ~4-way, one-time cost
    for (int idx = tid; idx < NF * LSEG; idx += TPB) {
        const int f = idx / LSEG;
        const int l = idx - f * LSEG;     // lstart + l <= lstart + 307 <= 2047
        fs[l * FSW + f] = xb[(size_t)f * LLEN + lstart + l];
    }
    __syncthreads();

    // ---------- stats: (f, t) -> mu, n = sqrt(G - 20 mu^2) ----------
    for (int idx = tid; idx < NF * TSLAB; idx += TPB) {
        const int f = idx / TSLAB;
        const int t = idx - f * TSLAB;
        const float* p0 = &fs[(off + t * 5) * FSW + f];
        float S = 0.f, G = 0.f;
        #pragma unroll
        for (int k = 0; k < 20; ++k) {
            const float v = p0[k * FSW];
            S += v;
            G = fmaf(v, v, G);
        }
        const float mu = S * 0.05f;
        const float nn = sqrtf(fmaxf(G - 20.f * mu * mu, 0.f));
        st[f * STSTR + t] = make_float2(mu, nn);
    }
    __syncthreads();

    // ---------- main: wave = pair-block, lane = t ----------
    const int wv = tid >> 6;              // 0..11
    const int t  = tid & 63;              // lane
    const int pb = g * 12 + wv;           // 0..35 (wave-uniform)
    int bi = 0, r2 = pb;
    while (r2 >= 8 - bi) { r2 -= 8 - bi; ++bi; }
    const int bj = bi + r2;

    if (t < TSLAB) {
        float A[4][4];
        #pragma unroll
        for (int r = 0; r < 4; ++r)
            #pragma unroll
            for (int c = 0; c < 4; ++c) A[r][c] = 0.f;

        const float* pi = &fs[(off + t * 5) * FSW + bi * 4];
        const float* pj = &fs[(off + t * 5) * FSW + bj * 4];
        #pragma unroll
        for (int k = 0; k < 20; ++k) {
            const float4 vi = *(const float4*)&pi[k * FSW];   // base + imm offset
            const float4 vj = *(const float4*)&pj[k * FSW];
            const float xi[4] = {vi.x, vi.y, vi.z, vi.w};
            const float xj[4] = {vj.x, vj.y, vj.z, vj.w};
            #pragma unroll
            for (int r = 0; r < 4; ++r)
                #pragma unroll
                for (int c = 0; c < 4; ++c)
                    A[r][c] = fmaf(xi[r], xj[c], A[r][c]);
        }

        float2 si[4], sj[4];
        #pragma unroll
        for (int r = 0; r < 4; ++r) {
            si[r] = st[(bi * 4 + r) * STSTR + t];
            sj[r] = st[(bj * 4 + r) * STSTR + t];
        }

        const int tg = s * TSLAB + t;     // global t, <= 405
        #pragma unroll
        for (int r = 0; r < 4; ++r) {
            const int fi = bi * 4 + r;
            #pragma unroll
            for (int c = 0; c < 4; ++c) {
                const int fj = bj * 4 + c;
                if (fj > fi) {            // always true off-diag; upper-tri on diag
                    const int p = fi * (63 - fi) / 2 + (fj - fi - 1);
                    const float num = A[r][c] - 20.f * si[r].x * sj[c].x;
                    const float den = si[r].y * sj[c].y + 1e-8f;
                    out[((size_t)b * NPAIR + p) * T_TOT + tg] =
                        num * __builtin_amdgcn_rcpf(den);
                }
            }
        }
    }
}

extern "C" void kernel_launch(void* const* d_in, const int* in_sizes, int n_in,
                              void* d_out, int out_size, void* d_ws, size_t ws_size,
                              hipStream_t stream) {
    (void)in_sizes; (void)n_in; (void)out_size; (void)d_ws; (void)ws_size;
    const float* x = (const float*)d_in[0];
    float* out     = (float*)d_out;
    const int nblocks = 8 * 32 * 21;      // 5376 = 3 pb-groups x 7 slabs x 256 batches
    hipLaunchKernelGGL(tscorr_kernel, dim3(nblocks), dim3(TPB), 0, stream, x, out);
}

// Round 7
// 162.417 us; speedup vs baseline: 27.5997x; 4.9772x over previous
//
#include <hip/hip_runtime.h>

#define TPB    256
#define NF     32
#define T_TOT  406
#define LLEN   2048
#define NPAIR  496
#define NCH    58           // chunks per batch; 58*7 = 406 exactly
#define CPW    7            // windows per chunk
#define FSW    36           // fs row stride (words): bank = (4*l + f) % 32, row-dependent
#define ROWS   56           // staged rows: off(<=3) + 6*5 + 20 = 53 max
#define OTS    8            // ot row stride

__global__ __launch_bounds__(TPB)
void tscorr_kernel(const float* __restrict__ x, float* __restrict__ out) {
    __shared__ float fs[ROWS * FSW];     //  8064 B, [l][f]
    __shared__ float ot[NPAIR * OTS];    // 15872 B, swizzled out tile

    const int tid = threadIdx.x;

    // XCD-pinned decode: all 58 chunks of batch b run on XCD b%8
    const int n     = blockIdx.x;
    const int xcd   = n & 7;
    const int slot  = n >> 3;            // 0..1855
    const int bidx  = slot / NCH;        // 0..31
    const int chunk = slot - bidx * NCH; // 0..57
    const int b     = xcd + 8 * bidx;

    const int l0     = chunk * (CPW * 5);    // chunk*35
    const int lstart = l0 & ~3;              // 16B-aligned
    const int off    = l0 - lstart;          // 0..3
    const float* xb  = x + (size_t)b * NF * LLEN;

    // ---------------- stage: coalesced float4 loads -> fs[l][f] ----------------
    {
        const int f  = tid >> 3;             // 0..31
        const int p4 = tid & 7;              // 0..7
        #pragma unroll
        for (int it = 0; it < 2; ++it) {
            const int grp = p4 + it * 8;     // 0..15
            if (grp < 14) {                  // 14*4 = 56 rows
                const int pos = grp * 4;
                // lstart+pos+3 <= 1992+55 = 2047: always in bounds
                const float4 v = *(const float4*)&xb[f * LLEN + lstart + pos];
                fs[(pos + 0) * FSW + f] = v.x;
                fs[(pos + 1) * FSW + f] = v.y;
                fs[(pos + 2) * FSW + f] = v.z;
                fs[(pos + 3) * FSW + f] = v.w;
            }
        }
    }
    __syncthreads();

    // ---------------- main: thread = (pair-block pb, window tl) ----------------
    const bool active = (tid < 252);
    const int  tl = tid / 36;                // 0..6
    const int  pb = tid - tl * 36;           // 0..35
    int bi = 0, r2 = active ? pb : 0;
    while (r2 >= 8 - bi) { r2 -= 8 - bi; ++bi; }
    const int bj = bi + r2;

    if (active) {
        float A[4][4];
        float Si[4], Sj[4], Gi[4], Gj[4];
        #pragma unroll
        for (int r = 0; r < 4; ++r) {
            Si[r] = Sj[r] = Gi[r] = Gj[r] = 0.f;
            #pragma unroll
            for (int c = 0; c < 4; ++c) A[r][c] = 0.f;
        }

        const float* pi = &fs[(off + tl * 5) * FSW + bi * 4];
        const float* pj = &fs[(off + tl * 5) * FSW + bj * 4];
        #pragma unroll
        for (int k = 0; k < 20; ++k) {
            const float4 vi = *(const float4*)&pi[k * FSW];   // base + imm offset
            const float4 vj = *(const float4*)&pj[k * FSW];
            const float xi[4] = {vi.x, vi.y, vi.z, vi.w};
            const float xj[4] = {vj.x, vj.y, vj.z, vj.w};
            #pragma unroll
            for (int r = 0; r < 4; ++r) {
                #pragma unroll
                for (int c = 0; c < 4; ++c)
                    A[r][c] = fmaf(xi[r], xj[c], A[r][c]);
                Si[r] += xi[r];
                Sj[r] += xj[r];
                Gi[r] = fmaf(xi[r], xi[r], Gi[r]);
                Gj[r] = fmaf(xj[r], xj[r], Gj[r]);
            }
        }

        // self-computed stats (registers only, overwrite S/G)
        float mi[4], ni[4], mj[4], nj[4];
        #pragma unroll
        for (int r = 0; r < 4; ++r) {
            mi[r] = Si[r] * 0.05f;
            ni[r] = sqrtf(fmaxf(Gi[r] - 20.f * mi[r] * mi[r], 0.f));
            mj[r] = Sj[r] * 0.05f;
            nj[r] = sqrtf(fmaxf(Gj[r] - 20.f * mj[r] * mj[r], 0.f));
        }

        #pragma unroll
        for (int r = 0; r < 4; ++r) {
            const int fi = bi * 4 + r;
            #pragma unroll
            for (int c = 0; c < 4; ++c) {
                const int fj = bj * 4 + c;
                if (fj > fi) {
                    const int p = fi * (63 - fi) / 2 + (fj - fi - 1);
                    const float num = A[r][c] - 20.f * mi[r] * mj[c];
                    const float den = ni[r] * nj[c] + 1e-8f;
                    // swizzled slot spreads banks: bank = (8p + (tl+p)&7) % 32
                    ot[p * OTS + ((tl + p) & 7)] = num * __builtin_amdgcn_rcpf(den);
                }
            }
        }
    }
    __syncthreads();

    // ---------------- sweep: ot -> out[b][p][chunk*7 + tw], coalesced ----------------
    float* ob = out + (size_t)b * NPAIR * T_TOT + chunk * CPW;
    for (int k = tid; k < NPAIR * OTS; k += TPB) {
        const int p    = k >> 3;
        const int slt  = k & 7;
        const int tw   = (slt - p) & 7;      // un-swizzle
        if (tw < CPW)
            ob[(size_t)p * T_TOT + tw] = ot[k];
    }
}

extern "C" void kernel_launch(void* const* d_in, const int* in_sizes, int n_in,
                              void* d_out, int out_size, void* d_ws, size_t ws_size,
                              hipStream_t stream) {
    (void)in_sizes; (void)n_in; (void)out_size; (void)d_ws; (void)ws_size;
    const float* x = (const float*)d_in[0];
    float* out     = (float*)d_out;
    const int nblocks = 8 * 32 * NCH;        // 14848
    hipLaunchKernelGGL(tscorr_kernel, dim3(nblocks), dim3(TPB), 0, stream, x, out);
}

// Round 8
// 101.158 us; speedup vs baseline: 44.3132x; 1.6056x over previous
//
#include <hip/hip_runtime.h>

#define TPB    256
#define NF     32
#define T_TOT  406
#define LLEN   2048
#define NPAIR  496
#define NCH    58           // chunks per batch; 58*7 = 406 exactly
#define CPW    7            // windows per chunk
#define FSW    36           // fs row stride (words): bank = (4*l + f) % 32, row-dependent
#define ROWS   56           // staged rows: off(<=3) + 6*5 + 19 = 52 max
#define OTS    8            // ot row stride

__global__ __launch_bounds__(TPB)
void tscorr_kernel(const float* __restrict__ x, float* __restrict__ out) {
    __shared__ float  fs[ROWS * FSW];    //  8064 B, [l][f]
    __shared__ float2 st[NF * 8];        //  2048 B, (sqrt20*mu, n) per (f, t)
    __shared__ float  ot[NPAIR * OTS];   // 15872 B, swizzled out tile

    const int tid = threadIdx.x;

    // XCD-pinned decode: all 58 chunks of batch b run on XCD b%8
    const int n     = blockIdx.x;
    const int xcd   = n & 7;
    const int slot  = n >> 3;            // 0..1855
    const int bidx  = slot / NCH;        // 0..31
    const int chunk = slot - bidx * NCH; // 0..57
    const int b     = xcd + 8 * bidx;

    const int l0     = chunk * (CPW * 5);    // chunk*35
    const int lstart = l0 & ~3;              // 16B-aligned
    const int off    = l0 - lstart;          // 0..3
    const float* xb  = x + (size_t)b * NF * LLEN;

    // ---------------- stage: coalesced float4 loads -> fs[l][f] ----------------
    {
        const int f  = tid >> 3;             // 0..31
        const int p4 = tid & 7;              // 0..7
        #pragma unroll
        for (int it = 0; it < 2; ++it) {
            const int grp = p4 + it * 8;     // 0..15
            if (grp < 14) {                  // 14*4 = 56 rows
                const int pos = grp * 4;
                // lstart+pos+3 <= 1992+55 = 2047: always in bounds
                const float4 v = *(const float4*)&xb[f * LLEN + lstart + pos];
                fs[(pos + 0) * FSW + f] = v.x;
                fs[(pos + 1) * FSW + f] = v.y;
                fs[(pos + 2) * FSW + f] = v.z;
                fs[(pos + 3) * FSW + f] = v.w;
            }
        }
    }
    __syncthreads();

    // ---------------- cooperative stats: thread = (t, f), conflict-free columns ----
    if (tid < NF * CPW) {                    // 224 threads
        const int t = tid >> 5;              // 0..6
        const int f = tid & 31;              // lanes span all 32 banks
        const float* p0 = &fs[(off + t * 5) * FSW + f];
        float S = 0.f, G = 0.f;
        #pragma unroll
        for (int k = 0; k < 20; ++k) {
            const float v = p0[k * FSW];
            S += v;
            G = fmaf(v, v, G);
        }
        const float mu = S * 0.05f;
        const float nn = sqrtf(fmaxf(G - 20.f * mu * mu, 0.f));
        // store sqrt(20)*mu so epilogue does num = A - pi*pj (no 20x mul)
        st[f * 8 + t] = make_float2(S * 0.2236067977f, nn);
    }

    // ---------------- main: thread = (pair-block pb, window tl), pure Gram ------
    const bool active = (tid < 252);
    const int  tl = tid / 36;                // 0..6
    const int  pb = tid - tl * 36;           // 0..35
    int bi = 0, r2 = active ? pb : 0;
    while (r2 >= 8 - bi) { r2 -= 8 - bi; ++bi; }
    const int bj = bi + r2;

    float A[4][4];
    if (active) {
        #pragma unroll
        for (int r = 0; r < 4; ++r)
            #pragma unroll
            for (int c = 0; c < 4; ++c) A[r][c] = 0.f;

        const float* pi = &fs[(off + tl * 5) * FSW + bi * 4];
        const float* pj = &fs[(off + tl * 5) * FSW + bj * 4];
        #pragma unroll
        for (int k = 0; k < 20; ++k) {
            const float4 vi = *(const float4*)&pi[k * FSW];   // base + imm offset
            const float4 vj = *(const float4*)&pj[k * FSW];
            const float xi[4] = {vi.x, vi.y, vi.z, vi.w};
            const float xj[4] = {vj.x, vj.y, vj.z, vj.w};
            #pragma unroll
            for (int r = 0; r < 4; ++r)
                #pragma unroll
                for (int c = 0; c < 4; ++c)
                    A[r][c] = fmaf(xi[r], xj[c], A[r][c]);
        }
    }
    __syncthreads();                          // st visible to all

    // ---------------- epilogue: normalize + staged ot write ----------------
    if (active) {
        float2 si[4], sj[4];
        #pragma unroll
        for (int r = 0; r < 4; ++r) {
            si[r] = st[(bi * 4 + r) * 8 + tl];   // 8 distinct addrs -> broadcast
            sj[r] = st[(bj * 4 + r) * 8 + tl];
        }
        #pragma unroll
        for (int r = 0; r < 4; ++r) {
            const int fi = bi * 4 + r;
            #pragma unroll
            for (int c = 0; c < 4; ++c) {
                const int fj = bj * 4 + c;
                if (fj > fi) {
                    const int p = fi * (63 - fi) / 2 + (fj - fi - 1);
                    const float num = A[r][c] - si[r].x * sj[c].x;
                    const float den = si[r].y * sj[c].y + 1e-8f;
                    ot[p * OTS + ((tl + p) & 7)] = num * __builtin_amdgcn_rcpf(den);
                }
            }
        }
    }
    __syncthreads();

    // ---------------- sweep: ot -> out[b][p][chunk*7 + tw], coalesced ----------------
    float* ob = out + (size_t)b * NPAIR * T_TOT + chunk * CPW;
    for (int k = tid; k < NPAIR * OTS; k += TPB) {
        const int p   = k >> 3;
        const int slt = k & 7;
        const int tw  = (slt - p) & 7;       // un-swizzle
        if (tw < CPW)
            ob[(size_t)p * T_TOT + tw] = ot[k];
    }
}

extern "C" void kernel_launch(void* const* d_in, const int* in_sizes, int n_in,
                              void* d_out, int out_size, void* d_ws, size_t ws_size,
                              hipStream_t stream) {
    (void)in_sizes; (void)n_in; (void)out_size; (void)d_ws; (void)ws_size;
    const float* x = (const float*)d_in[0];
    float* out     = (float*)d_out;
    const int nblocks = 8 * 32 * NCH;        // 14848
    hipLaunchKernelGGL(tscorr_kernel, dim3(nblocks), dim3(TPB), 0, stream, x, out);
}

// Round 9
// 87.970 us; speedup vs baseline: 50.9563x; 1.1499x over previous
//
#include <hip/hip_runtime.h>

#define TPB    256
#define NF     32
#define T_TOT  406
#define LLEN   2048
#define NPAIR  496
#define NCH    29          // chunks per batch; 29*14 = 406 exactly
#define WPB    14          // windows per chunk (7 window-pairs)
#define FSW    36          // fs row stride (words): bank-rotating, b128-friendly
#define ROWS   88          // staged rows: off(<=2) + 6*10 + 25 = 87 max
#define STSTR  15          // st row stride (float2), odd -> 2-way-free epilogue reads
#define OTS    8           // ot row stride (u32 slots, 7 used, swizzled)

__device__ __forceinline__ unsigned int f2bf(float f) {
    unsigned int u = __float_as_uint(f);
    u += 0x7fffu + ((u >> 16) & 1u);           // RNE
    return u >> 16;
}

__global__ __launch_bounds__(TPB)
void tscorr_kernel(const float* __restrict__ x, float* __restrict__ out) {
    __shared__ float        fs[ROWS * FSW];    // 12672 B, [l][f]
    __shared__ float2       st[NF * STSTR];    //  3840 B, (sqrt20*mu, n) per (f,t)
    __shared__ unsigned int ot[NPAIR * OTS];   // 15872 B, 2xbf16-packed out tile

    const int tid = threadIdx.x;

    // XCD-pinned decode: all 29 chunks of batch b run on XCD b%8
    const int n     = blockIdx.x;
    const int xcd   = n & 7;
    const int slot  = n >> 3;            // 0..927
    const int bidx  = slot / NCH;        // 0..31
    const int chunk = slot - bidx * NCH; // 0..28
    const int b     = xcd + 8 * bidx;

    const int l0     = chunk * (WPB * 5);    // chunk*70
    const int lstart = l0 & ~3;              // 16B-aligned
    const int off    = l0 - lstart;          // 0 or 2
    const float* xb  = x + (size_t)b * NF * LLEN;

    // ---------------- stage: coalesced float4 loads -> fs[l][f] ----------------
    {
        const int f  = tid >> 3;             // 0..31
        const int p4 = tid & 7;              // 0..7
        #pragma unroll
        for (int it = 0; it < 3; ++it) {
            const int grp = p4 + it * 8;     // 0..23
            if (grp < 22) {                  // 22*4 = 88 rows
                const int pos = grp * 4;
                // lstart+pos+3 <= 1960+87 = 2047: always in bounds
                const float4 v = *(const float4*)&xb[f * LLEN + lstart + pos];
                fs[(pos + 0) * FSW + f] = v.x;
                fs[(pos + 1) * FSW + f] = v.y;
                fs[(pos + 2) * FSW + f] = v.z;
                fs[(pos + 3) * FSW + f] = v.w;
            }
        }
    }
    __syncthreads();

    // ------------- cooperative stats: (f, tloc) columns, conflict-free -------------
    for (int idx = tid; idx < NF * WPB; idx += TPB) {   // 448 columns, 2 passes
        const int tloc = idx >> 5;           // 0..13
        const int f    = idx & 31;           // lanes span all 32 banks
        const float* p0 = &fs[(off + tloc * 5) * FSW + f];
        float S = 0.f, G = 0.f;
        #pragma unroll
        for (int k = 0; k < 20; ++k) {
            const float v = p0[k * FSW];
            S += v;
            G = fmaf(v, v, G);
        }
        const float p  = S * 0.2236067977f;  // sqrt(20)*mu = S/sqrt(20)
        const float nn = sqrtf(fmaxf(G - p * p, 0.f));
        st[f * STSTR + tloc] = make_float2(p, nn);
    }

    // -------- main: thread = (pair-block pb, window-pair wp), 2 windows/thread -----
    const bool active = (tid < 252);
    const int  wp = tid / 36;                // 0..6
    const int  pb = tid - wp * 36;           // 0..35
    int bi = 0, r2 = active ? pb : 0;
    while (r2 >= 8 - bi) { r2 -= 8 - bi; ++bi; }
    const int bj = bi + r2;

    float A0[4][4], A1[4][4];
    if (active) {
        #pragma unroll
        for (int r = 0; r < 4; ++r)
            #pragma unroll
            for (int c = 0; c < 4; ++c) { A0[r][c] = 0.f; A1[r][c] = 0.f; }

        const float* pi = &fs[(off + wp * 10) * FSW + bi * 4];
        const float* pj = &fs[(off + wp * 10) * FSW + bj * 4];
        #pragma unroll
        for (int k = 0; k < 25; ++k) {       // windows share 15 of 25 rows
            const float4 vi = *(const float4*)&pi[k * FSW];   // base + imm offset
            const float4 vj = *(const float4*)&pj[k * FSW];
            const float xi[4] = {vi.x, vi.y, vi.z, vi.w};
            const float xj[4] = {vj.x, vj.y, vj.z, vj.w};
            if (k < 20) {
                #pragma unroll
                for (int r = 0; r < 4; ++r)
                    #pragma unroll
                    for (int c = 0; c < 4; ++c)
                        A0[r][c] = fmaf(xi[r], xj[c], A0[r][c]);
            }
            if (k >= 5) {
                #pragma unroll
                for (int r = 0; r < 4; ++r)
                    #pragma unroll
                    for (int c = 0; c < 4; ++c)
                        A1[r][c] = fmaf(xi[r], xj[c], A1[r][c]);
            }
        }
    }
    __syncthreads();                          // st visible

    // ---------------- epilogue: normalize both windows, pack 2xbf16 ----------------
    if (active) {
        const int t0 = 2 * wp;                // local even window
        float2 sj0[4], sj1[4];
        #pragma unroll
        for (int c = 0; c < 4; ++c) {
            sj0[c] = st[(bj * 4 + c) * STSTR + t0];
            sj1[c] = st[(bj * 4 + c) * STSTR + t0 + 1];
        }
        #pragma unroll
        for (int r = 0; r < 4; ++r) {
            const int fi = bi * 4 + r;
            const float2 si0 = st[fi * STSTR + t0];
            const float2 si1 = st[fi * STSTR + t0 + 1];
            #pragma unroll
            for (int c = 0; c < 4; ++c) {
                const int fj = bj * 4 + c;
                if (fj > fi) {
                    const int p = fi * (63 - fi) / 2 + (fj - fi - 1);
                    const float num0 = A0[r][c] - si0.x * sj0[c].x;
                    const float den0 = si0.y * sj0[c].y + 1e-8f;
                    const float num1 = A1[r][c] - si1.x * sj1[c].x;
                    const float den1 = si1.y * sj1[c].y + 1e-8f;
                    const float v0 = num0 * __builtin_amdgcn_rcpf(den0);
                    const float v1 = num1 * __builtin_amdgcn_rcpf(den1);
                    ot[p * OTS + ((wp + p) & 7)] = f2bf(v0) | (f2bf(v1) << 16);
                }
            }
        }
    }
    __syncthreads();

    // ------------- sweep: ot -> out[b][p][chunk*14 + 2wp + {0,1}], float2 ----------
    float* ob = out + (size_t)b * NPAIR * T_TOT + chunk * WPB;
    for (int k = tid; k < NPAIR * OTS; k += TPB) {
        const int p   = k >> 3;
        const int slt = k & 7;
        const int wpo = (slt - p) & 7;       // un-swizzle
        if (wpo < 7) {
            const unsigned int v = ot[k];
            float2 o;
            o.x = __uint_as_float((v & 0xffffu) << 16);
            o.y = __uint_as_float(v & 0xffff0000u);
            *(float2*)&ob[(size_t)p * T_TOT + 2 * wpo] = o;   // 8B aligned
        }
    }
}

extern "C" void kernel_launch(void* const* d_in, const int* in_sizes, int n_in,
                              void* d_out, int out_size, void* d_ws, size_t ws_size,
                              hipStream_t stream) {
    (void)in_sizes; (void)n_in; (void)out_size; (void)d_ws; (void)ws_size;
    const float* x = (const float*)d_in[0];
    float* out     = (float*)d_out;
    const int nblocks = 8 * 32 * NCH;        // 7424
    hipLaunchKernelGGL(tscorr_kernel, dim3(nblocks), dim3(TPB), 0, stream, x, out);
}